// Round 6
// baseline (335.848 us; speedup 1.0000x reference)
//
#include <hip/hip_runtime.h>
#include <math.h>

#define D 128
#define B_SZ 1024
#define KNB 200
#define AW 392    // Ah LDS stride (halves): 784 B -> 196 f32 banks %32 = 4 (2-way, free)
#define SCW 1028  // scores LDS stride (f32)
#define PW 1032   // P LDS stride (halves)

typedef _Float16 half8 __attribute__((ext_vector_type(8)));
typedef _Float16 half4 __attribute__((ext_vector_type(4)));
typedef float floatx4 __attribute__((ext_vector_type(4)));

__device__ __forceinline__ float sigmoid_f(float x) { return 1.f / (1.f + __expf(-x)); }
__device__ __forceinline__ float tanh_fast(float x) { return 1.f - 2.f / (__expf(2.f * x) + 1.f); }

// ---------------------------------------------------------------------------
// Kernel 0: one-time fp16 LSTM weights, unified [1024][384]:
// row u = [w_ih[u,0:128] | w_hh[u,0:256]]. 192 blocks x 256 thr.
// ---------------------------------------------------------------------------
__global__ __launch_bounds__(256) void k_cvtw(
    const float* __restrict__ w_ih, const float* __restrict__ w_hh,
    _Float16* __restrict__ w16)
{
    const int i8 = (blockIdx.x * 256 + threadIdx.x) * 8;
    const int row = i8 / 384, k = i8 % 384;
    const float* src = (k < 128) ? &w_ih[row * 128 + k] : &w_hh[row * 256 + (k - 128)];
    float4 v0 = *(const float4*)src;
    float4 v1 = *(const float4*)(src + 4);
    half8 h;
    h[0] = (_Float16)v0.x; h[1] = (_Float16)v0.y; h[2] = (_Float16)v0.z; h[3] = (_Float16)v0.w;
    h[4] = (_Float16)v1.x; h[5] = (_Float16)v1.y; h[6] = (_Float16)v1.z; h[7] = (_Float16)v1.w;
    *(half8*)&w16[i8] = h;
}

// ---------------------------------------------------------------------------
// Kernel 1: gather+sum, GCN linear, support encoder, query gather.
// One block per batch row b, 512 threads. (Known wall: random 512-B gathers
// pin at ~1.25 TB/s L2-miss BW regardless of occupancy/vectorization.)
// ---------------------------------------------------------------------------
__global__ __launch_bounds__(512) void k_support(
    const int* __restrict__ relations, const int* __restrict__ entities,
    const int* __restrict__ query, const float* __restrict__ emb,
    const float* __restrict__ gcn_w, const float* __restrict__ gcn_b,
    const float* __restrict__ p1_w, const float* __restrict__ p1_b,
    const float* __restrict__ p2_w, const float* __restrict__ p2_b,
    const float* __restrict__ ln_a, const float* __restrict__ ln_b,
    float* __restrict__ sg, _Float16* __restrict__ sgH, _Float16* __restrict__ sgT,
    _Float16* __restrict__ qbH)
{
    __shared__ int idxs[2 * KNB];
    __shared__ __align__(16) float part[16][132];
    __shared__ __align__(16) float S[2 * D];
    __shared__ __align__(16) float sup[D];
    __shared__ __align__(16) float hid[2 * D];
    __shared__ __align__(16) float zv[D];
    __shared__ float red2[2];

    const int b = blockIdx.x;
    const int t = threadIdx.x;

    if (t < KNB) idxs[t] = relations[b * KNB + t];
    else if (t < 2 * KNB) idxs[t] = entities[b * KNB + (t - KNB)];
    __syncthreads();

    {
        const int g = t >> 5, c4 = (t & 31) * 4;
        const int* mi = &idxs[(g >> 3) * KNB];
        float4 a4 = make_float4(0.f, 0.f, 0.f, 0.f);
        #pragma unroll 5
        for (int k = (g & 7); k < KNB; k += 8) {
            float4 v = *(const float4*)&emb[(size_t)mi[k] * D + c4];
            a4.x += v.x; a4.y += v.y; a4.z += v.z; a4.w += v.w;
        }
        *(float4*)&part[g][c4] = a4;
    }
    __syncthreads();
    if (t < 2 * D) {
        const int half = t >> 7, c = t & 127;
        float s = 0.f;
        #pragma unroll
        for (int j = 0; j < 8; ++j) s += part[half * 8 + j][c];
        S[t] = s;
    }
    __syncthreads();

    if (t < D) {
        const float4* w4 = (const float4*)(gcn_w + t * 2 * D);
        float dot = 0.f;
        #pragma unroll 8
        for (int f = 0; f < 2 * D / 4; ++f) {
            float4 w = w4[f];
            float4 s = *(const float4*)&S[f * 4];
            dot += w.x * s.x + w.y * s.y + w.z * s.z + w.w * s.w;
        }
        float v = (dot + 200.f * gcn_b[t]) * (1.f / 1024.f);  // num_neighbors = B = 1024
        sup[t] = tanhf(v);
    }
    __syncthreads();

    if (t < 2 * D) {
        const float4* w4 = (const float4*)(p1_w + t * D);
        float dot = 0.f;
        #pragma unroll 8
        for (int f = 0; f < D / 4; ++f) {
            float4 w = w4[f];
            float4 s = *(const float4*)&sup[f * 4];
            dot += w.x * s.x + w.y * s.y + w.z * s.z + w.w * s.w;
        }
        float h = dot + p1_b[t];
        hid[t] = h > 0.f ? h : 0.f;
    }
    __syncthreads();

    if (t < D) {
        const float4* w4 = (const float4*)(p2_w + t * 2 * D);
        float dot = 0.f;
        #pragma unroll 8
        for (int f = 0; f < 2 * D / 4; ++f) {
            float4 w = w4[f];
            float4 s = *(const float4*)&hid[f * 4];
            dot += w.x * s.x + w.y * s.y + w.z * s.z + w.w * s.w;
        }
        zv[t] = dot + p2_b[t] + sup[t];
    }
    __syncthreads();

    if (t < 64) {
        float x0 = zv[t], x1 = zv[t + 64];
        float s = x0 + x1;
        for (int off = 32; off; off >>= 1) s += __shfl_down(s, off);
        float mu = __shfl(s, 0) * (1.f / 128.f);
        float d0 = x0 - mu, d1 = x1 - mu;
        float v = d0 * d0 + d1 * d1;
        for (int off = 32; off; off >>= 1) v += __shfl_down(v, off);
        v = __shfl(v, 0);
        if (t == 0) { red2[0] = mu; red2[1] = sqrtf(v * (1.f / 127.f)); }
    }
    __syncthreads();
    if (t < D) {
        float mu = red2[0], sigma = red2[1];
        float val = (zv[t] - mu) / (sigma + 1e-3f) * ln_a[t] + ln_b[t];
        sg[b * D + t] = val;
        sgH[b * D + t] = (_Float16)val;
        sgT[t * B_SZ + b] = (_Float16)val;
        qbH[b * D + t] = (_Float16)emb[(size_t)query[b] * D + t];
    }
}

// ---------------------------------------------------------------------------
// Kernel 2: FUSED 4-step LSTM+attention chain + cosine.
// Rows are independent given sg: 64 blocks x 16 rows, 512 threads (8 waves).
// Wave wv owns gate-units [wv*32, wv*32+32) (all 4 gates) and r-cols
// [wv*16, wv*16+16). g_q = q@w_ih^T cached in registers across steps.
// LDS: Ah = [q | h | r] fp16 A-operand, Sc = scores f32, P = exp fp16.
// ---------------------------------------------------------------------------
__global__ __launch_bounds__(512) void k_chain(
    const _Float16* __restrict__ qbH, const _Float16* __restrict__ sgH,
    const _Float16* __restrict__ sgT, const float* __restrict__ sg,
    const _Float16* __restrict__ w16, const float* __restrict__ b_ih,
    const float* __restrict__ b_hh, float* __restrict__ out)
{
    __shared__ _Float16 Ah[16 * AW];      // [16][392]: 0:128 q | 128:256 h | 256:384 r
    __shared__ float    Sc[16 * SCW];     // scores f32
    __shared__ _Float16 P[16 * PW];       // exp(s - mx), unscaled
    __shared__ float    smx[16];
    __shared__ float    sinv[16];
    __shared__ float    hsave[16 * 132];  // final h_out f32

    const int t = threadIdx.x;
    const int wv = t >> 6, lane = t & 63;
    const int m = lane & 15, quad = lane >> 4;
    const int b0 = blockIdx.x * 16;

    // stage q rows into Ah[:, 0:128]
    if (t < 256) {
        const int row = t >> 4, ch = (t & 15) * 8;
        *(half8*)&Ah[row * AW + ch] = *(const half8*)&qbH[(b0 + row) * D + ch];
    }

    // bias registers: wave wv's units, both 16-tiles, 4 gates
    float bi[2][4];
    #pragma unroll
    for (int u = 0; u < 2; ++u) {
        const int unit = wv * 32 + u * 16 + m;
        #pragma unroll
        for (int g = 0; g < 4; ++g) bi[u][g] = b_ih[g * 256 + unit] + b_hh[g * 256 + unit];
    }

    floatx4 cfr[2];
    floatx4 gq[2][4];
    floatx4 acc[2][4];
    #pragma unroll
    for (int u = 0; u < 2; ++u) {
        #pragma unroll
        for (int i = 0; i < 4; ++i) cfr[u][i] = 0.f;
        #pragma unroll
        for (int g = 0; g < 4; ++g)
            #pragma unroll
            for (int i = 0; i < 4; ++i) gq[u][g][i] = 0.f;
    }

    __syncthreads();

    // ---- g_q = q @ w_ih^T  (K=128), cached across all steps
    #pragma unroll
    for (int ks = 0; ks < 4; ++ks) {
        half8 a = *(const half8*)&Ah[m * AW + ks * 32 + quad * 8];
        #pragma unroll
        for (int u = 0; u < 2; ++u)
            #pragma unroll
            for (int g = 0; g < 4; ++g) {
                half8 bf = *(const half8*)&w16[(g * 256 + wv * 32 + u * 16 + m) * 384 + ks * 32 + quad * 8];
                gq[u][g] = __builtin_amdgcn_mfma_f32_16x16x32_f16(a, bf, gq[u][g], 0, 0, 0);
            }
    }

    auto gates_hr = [&]() {  // acc = gq + h_r @ w_hh^T  (K=256)
        #pragma unroll
        for (int u = 0; u < 2; ++u)
            #pragma unroll
            for (int g = 0; g < 4; ++g) acc[u][g] = gq[u][g];
        #pragma unroll
        for (int ks = 0; ks < 8; ++ks) {
            half8 a = *(const half8*)&Ah[m * AW + 128 + ks * 32 + quad * 8];
            #pragma unroll
            for (int u = 0; u < 2; ++u)
                #pragma unroll
                for (int g = 0; g < 4; ++g) {
                    half8 bf = *(const half8*)&w16[(g * 256 + wv * 32 + u * 16 + m) * 384 + 128 + ks * 32 + quad * 8];
                    acc[u][g] = __builtin_amdgcn_mfma_f32_16x16x32_f16(a, bf, acc[u][g], 0, 0, 0);
                }
        }
    };

    auto pointwise = [&](bool first, bool save) {
        __syncthreads();  // all waves done reading Ah before h is overwritten
        #pragma unroll
        for (int u = 0; u < 2; ++u) {
            const int unit = wv * 32 + u * 16 + m;
            #pragma unroll
            for (int rr = 0; rr < 4; ++rr) {
                float gi = acc[u][0][rr] + bi[u][0];
                float gf = acc[u][1][rr] + bi[u][1];
                float gg = acc[u][2][rr] + bi[u][2];
                float go = acc[u][3][rr] + bi[u][3];
                float cold = first ? 0.f : cfr[u][rr];
                float cn = sigmoid_f(gf) * cold + sigmoid_f(gi) * tanh_fast(gg);
                cfr[u][rr] = cn;
                if (wv < 4) {  // units 0..127 -> h_out
                    const int row = quad * 4 + rr;
                    float qv = (float)Ah[row * AW + unit];
                    float ho = qv + sigmoid_f(go) * tanh_fast(cn);
                    Ah[row * AW + 128 + unit] = (_Float16)ho;
                    if (save) hsave[row * 132 + unit] = ho;
                }
            }
        }
    };

    auto attn = [&]() {
        __syncthreads();  // h writes visible
        // scores: wave wv -> j-tiles wv*8 .. wv*8+7
        #pragma unroll
        for (int i = 0; i < 8; ++i) {
            const int j0 = (wv * 8 + i) * 16;
            floatx4 a2;
            #pragma unroll
            for (int z = 0; z < 4; ++z) a2[z] = 0.f;
            #pragma unroll
            for (int ks = 0; ks < 4; ++ks) {
                half8 a = *(const half8*)&Ah[m * AW + 128 + ks * 32 + quad * 8];
                half8 bf = *(const half8*)&sgH[(j0 + m) * D + ks * 32 + quad * 8];
                a2 = __builtin_amdgcn_mfma_f32_16x16x32_f16(a, bf, a2, 0, 0, 0);
            }
            #pragma unroll
            for (int rr = 0; rr < 4; ++rr)
                Sc[(quad * 4 + rr) * SCW + j0 + m] = a2[rr];
        }
        __syncthreads();
        // softmax: 32 threads per row
        {
            const int row = t >> 5, li = t & 31;
            float mm = -1e30f;
            #pragma unroll
            for (int j = 0; j < 32; ++j) mm = fmaxf(mm, Sc[row * SCW + li + j * 32]);
            #pragma unroll
            for (int off = 16; off; off >>= 1) mm = fmaxf(mm, __shfl_down(mm, off));
            if (li == 0) smx[row] = mm;
        }
        __syncthreads();
        {
            const int row = t >> 5, li = t & 31;
            const float mm = smx[row];
            float ss = 0.f;
            #pragma unroll
            for (int j = 0; j < 32; ++j) {
                float e = __expf(Sc[row * SCW + li + j * 32] - mm);
                P[row * PW + li + j * 32] = (_Float16)e;
                ss += e;
            }
            #pragma unroll
            for (int off = 16; off; off >>= 1) ss += __shfl_down(ss, off);
            if (li == 0) sinv[row] = 1.f / ss;
        }
        __syncthreads();
        // r = (P @ sg) * inv : wave wv -> r-cols wv*16..+16, full K=1024
        {
            floatx4 a3;
            #pragma unroll
            for (int z = 0; z < 4; ++z) a3[z] = 0.f;
            #pragma unroll 8
            for (int ks = 0; ks < 32; ++ks) {
                half8 a = *(const half8*)&P[m * PW + ks * 32 + quad * 8];
                half8 bf = *(const half8*)&sgT[(wv * 16 + m) * B_SZ + ks * 32 + quad * 8];
                a3 = __builtin_amdgcn_mfma_f32_16x16x32_f16(a, bf, a3, 0, 0, 0);
            }
            #pragma unroll
            for (int rr = 0; rr < 4; ++rr) {
                const int row = quad * 4 + rr;
                Ah[row * AW + 256 + wv * 16 + m] = (_Float16)(a3[rr] * sinv[row]);
            }
        }
        __syncthreads();
    };

    // ---- step 0: gates = g_q + bias (h_r == 0)
    #pragma unroll
    for (int u = 0; u < 2; ++u)
        #pragma unroll
        for (int g = 0; g < 4; ++g) acc[u][g] = gq[u][g];
    pointwise(true, false);
    attn();
    // ---- steps 1..2
    gates_hr(); pointwise(false, false); attn();
    gates_hr(); pointwise(false, false); attn();
    // ---- step 3 (attention dead)
    gates_hr(); pointwise(false, true);

    __syncthreads();
    // cosine: lanes of wave 0; row = t&15, part = t>>4 (4 parts x 32 cols)
    if (t < 64) {
        const int row = t & 15, part = t >> 4;
        float cr = 0.f, n1 = 0.f, n2 = 0.f;
        #pragma unroll 8
        for (int j = 0; j < 32; ++j) {
            const int c = part * 32 + j;
            float h = hsave[row * 132 + c];
            float s = sg[(b0 + row) * D + c];
            cr += h * s; n1 += h * h; n2 += s * s;
        }
        cr += __shfl_down(cr, 16); n1 += __shfl_down(n1, 16); n2 += __shfl_down(n2, 16);
        cr += __shfl_down(cr, 32); n1 += __shfl_down(n1, 32); n2 += __shfl_down(n2, 32);
        if (t < 16) out[b0 + row] = cr / sqrtf(n1 * n2);
    }
}

// ---------------------------------------------------------------------------
extern "C" void kernel_launch(void* const* d_in, const int* in_sizes, int n_in,
                              void* d_out, int out_size, void* d_ws, size_t ws_size,
                              hipStream_t stream)
{
    const int*   relations = (const int*)d_in[0];
    const int*   entities  = (const int*)d_in[1];
    const int*   query     = (const int*)d_in[2];
    const float* emb       = (const float*)d_in[3];
    const float* gcn_w     = (const float*)d_in[4];
    const float* gcn_b     = (const float*)d_in[5];
    const float* p1_w      = (const float*)d_in[6];
    const float* p1_b      = (const float*)d_in[7];
    const float* p2_w      = (const float*)d_in[8];
    const float* p2_b      = (const float*)d_in[9];
    const float* ln_a      = (const float*)d_in[10];
    const float* ln_b      = (const float*)d_in[11];
    const float* w_ih      = (const float*)d_in[12];
    const float* w_hh      = (const float*)d_in[13];
    const float* b_ih      = (const float*)d_in[14];
    const float* b_hh      = (const float*)d_in[15];

    // Workspace (float-slot offsets; fp16 1024x128 buffers = 65536 slots each)
    float* ws = (float*)d_ws;
    float*     sg  = ws;                          // 131072
    _Float16*  sgH = (_Float16*)(ws + 131072);    // 65536
    _Float16*  sgT = (_Float16*)(ws + 196608);    // 65536
    _Float16*  qbH = (_Float16*)(ws + 262144);    // 65536
    _Float16*  w16 = (_Float16*)(ws + 327680);    // 1024*384 halves = 196608 slots
    // end: 524288 floats = 2 MB

    k_cvtw<<<dim3(192), dim3(256), 0, stream>>>(w_ih, w_hh, w16);
    k_support<<<dim3(B_SZ), dim3(512), 0, stream>>>(
        relations, entities, query, emb, gcn_w, gcn_b,
        p1_w, p1_b, p2_w, p2_b, ln_a, ln_b, sg, sgH, sgT, qbH);
    k_chain<<<dim3(64), dim3(512), 0, stream>>>(
        qbH, sgH, sgT, sg, w16, b_ih, b_hh, (float*)d_out);
}